// Round 10
// baseline (142.448 us; speedup 1.0000x reference)
//
#include <hip/hip_runtime.h>

// B=32768, K=64, D=64, GAIN=1.0
#define LOG_2PI 1.8378770664093453f
#define LOG2E   1.4426950408889634f

typedef __attribute__((ext_vector_type(8))) short  short8;   // 8 x bf16
typedef __attribute__((ext_vector_type(4))) float  float4_;
typedef __attribute__((ext_vector_type(2))) unsigned int uint2_;

__device__ __forceinline__ unsigned short f2bf(float f) {
  unsigned u = __builtin_bit_cast(unsigned, f);
  u += 0x7fffu + ((u >> 16) & 1u);   // RNE
  return (unsigned short)(u >> 16);
}
__device__ __forceinline__ float hi2f(unsigned u) {        // bf16 in high half
  return __builtin_bit_cast(float, u & 0xffff0000u);
}
__device__ __forceinline__ float lo2f(unsigned u) {        // bf16 in low half
  return __builtin_bit_cast(float, u << 16);
}
template <int CTRL>
__device__ __forceinline__ float dpp_add(float v) {
  int t = __builtin_amdgcn_mov_dpp(__builtin_bit_cast(int, v), CTRL, 0xf, 0xf, true);
  return v + __builtin_bit_cast(float, t);
}

// ---------------------------------------------------------------------------
// Setup: one block per component k. Emits Wb (B-fragment-order bf16 image of
// -0.5*log2e*M), cvec (log2e*c), beta (log2e*(beta+90)). Zeroes out[0].
// ---------------------------------------------------------------------------
__global__ __launch_bounds__(256) void gmm_setup(
    const float* __restrict__ means_raw, const float* __restrict__ scale_raw,
    const float* __restrict__ weights_raw, unsigned short* __restrict__ Wb,
    float* __restrict__ cvec, float* __restrict__ beta,
    float* __restrict__ out)
{
  const int k = blockIdx.x;
  const int t = threadIdx.x;
  const int lane = t & 63;
  const int wv = t >> 6;
  const int q = lane >> 4;
  const int jj = lane & 15;

  if (k == 0 && t == 0) out[0] = 0.0f;

  __shared__ float Plt[64][68];   // Plt[m][i] = L[i][m] for i>m, else 0
  __shared__ float Vt[64][68];    // Vt[c][m]  = Linv[m][c]
  __shared__ __align__(16) unsigned short Vb[64][72];  // bf16 Vt image
  __shared__ float dg[64], rdg[64], mu_s[64], y_s[64];

  {  // phase 1
    const int i = t >> 2;
    const int c0 = (t & 3) * 16;
    float4_ v4[4];
    const float4_* src = (const float4_*)(scale_raw + (size_t)k * 4096 + i * 64 + c0);
    v4[0] = src[0]; v4[1] = src[1]; v4[2] = src[2]; v4[3] = src[3];
#pragma unroll
    for (int e = 0; e < 16; ++e) {
      const int c = c0 + e;
      const float val = ((const float*)v4)[e] * (1.0f / 512.0f);
      Plt[c][i] = (c < i) ? val : 0.0f;
      if (c == i) { dg[i] = val; rdg[i] = __expf(-val); }
    }
  }
  if (t < 64) mu_s[t] = means_raw[k * 64 + t] * (1.0f / 64.0f);
  __syncthreads();

  // phase 2: forward substitution (col j = wv*16+jj, rows [16q,16q+16))
  {
    const int j = wv * 16 + jj;
    float s[16];
#pragma unroll
    for (int i = 0; i < 16; ++i) s[i] = 0.0f;
#pragma unroll
    for (int m = 0; m < 64; ++m) {
      const float rm = rdg[m];
      float vcand = (m == j) ? rm : -s[m & 15] * rm;
      const float v = __shfl(vcand, (m >> 4) * 16 + jj, 64);
      if (q == (m >> 4)) {
        Vt[j][m] = v;
        Vb[j][m] = f2bf(v);
      }
      const float4_* prow = (const float4_*)&Plt[m][16 * q];
      const float4_ p0 = prow[0], p1 = prow[1], p2 = prow[2], p3 = prow[3];
      s[0]  += p0[0] * v; s[1]  += p0[1] * v; s[2]  += p0[2] * v; s[3]  += p0[3] * v;
      s[4]  += p1[0] * v; s[5]  += p1[1] * v; s[6]  += p1[2] * v; s[7]  += p1[3] * v;
      s[8]  += p2[0] * v; s[9]  += p2[1] * v; s[10] += p2[2] * v; s[11] += p2[3] * v;
      s[12] += p3[0] * v; s[13] += p3[1] * v; s[14] += p3[2] * v; s[15] += p3[3] * v;
    }
  }
  __syncthreads();

  // phase 3a: M = V^T V via MFMA; scatter -0.5*log2e*M into B-frag image
  {
    const short8 a0 = *(const short8*)&Vb[16 * wv + jj][8 * q];
    const short8 a1 = *(const short8*)&Vb[16 * wv + jj][8 * q + 32];
#pragma unroll
    for (int t4 = 0; t4 < 4; ++t4) {
      const short8 b0 = *(const short8*)&Vb[jj + 16 * t4][8 * q];
      const short8 b1 = *(const short8*)&Vb[jj + 16 * t4][8 * q + 32];
      float4_ f = {0.f, 0.f, 0.f, 0.f};
      f = __builtin_amdgcn_mfma_f32_16x16x32_bf16(a0, b0, f, 0, 0, 0);
      f = __builtin_amdgcn_mfma_f32_16x16x32_bf16(a1, b1, f, 0, 0, 0);
#pragma unroll
      for (int r = 0; r < 4; ++r) {
        const int kd = 16 * wv + 4 * q + r;       // M row (= kdim, symmetric)
        const int n  = jj + 16 * t4;              // M col (= n)
        const int addr = k * 4096 + (((kd >> 3) & 3) * 16 + (n & 15)) * 64
                       + (kd >> 5) * 32 + (n >> 4) * 8 + (kd & 7);
        Wb[addr] = f2bf(-0.5f * LOG2E * f[r]);
      }
    }
  }
  if (wv == 0) {  // y = V*mu
    float acc = 0.0f;
    for (int j2 = 0; j2 < 64; ++j2) acc += Vt[j2][lane] * mu_s[j2];
    y_s[lane] = acc;
  }
  __syncthreads();

  // tail: c' = log2e * V^T y, beta' = log2e*(beta+90)
  if (t < 64) {
    const int i = t;
    float ci = 0.0f;
#pragma unroll
    for (int m4 = 0; m4 < 16; ++m4) {
      const float4_ a4 = *(const float4_*)&Vt[i][4 * m4];
      const float4_ b4 = *(const float4_*)&y_s[4 * m4];
      ci += a4[0] * b4[0] + a4[1] * b4[1] + a4[2] * b4[2] + a4[3] * b4[3];
    }
    cvec[k * 64 + i] = LOG2E * ci;
    float rq  = ci * mu_s[i];
    float dgv = dg[i];
    const float wr = weights_raw[i] * 0.125f;
    float mx = wr;
#pragma unroll
    for (int d = 1; d < 64; d <<= 1) mx = fmaxf(mx, __shfl_xor(mx, d, 64));
    float se = __expf(wr - mx);
#pragma unroll
    for (int d = 1; d < 64; d <<= 1) {
      se  += __shfl_xor(se, d, 64);
      rq  += __shfl_xor(rq, d, 64);
      dgv += __shfl_xor(dgv, d, 64);
    }
    if (i == 0) {
      const float wrk  = weights_raw[k] * 0.125f;
      const float logw = wrk - mx - __logf(se);
      const float bval = -0.5f * rq - 32.0f * LOG_2PI - dgv + logw;
      beta[k] = LOG2E * (bval + 90.0f);
    }
  }
}

// ---------------------------------------------------------------------------
// Main: 512 blocks x 512 threads (8 waves); block owns 64 rows END-TO-END
// (4 m-tiles), staged once. Wave w handles comps w*8..w*8+7: per comp, load
// b-frags (8 dwordx4 from L2-resident Wb) + c/beta, run 4 m-tiles. A-frags
// hoisted to registers (LDS read once per wave — kills the per-iter lgkm
// stall of R9). Row exp-sums accumulate in registers (sacc[4][4]) across
// comps; cross-wave combine via block-local LDS rowacc; block finalizes its
// own 64 rows -> one atomicAdd(out). No global ph / done / fences.
// ---------------------------------------------------------------------------
__global__ __launch_bounds__(512) __attribute__((amdgpu_waves_per_eu(4, 4)))
void gmm_main(
    const float* __restrict__ x, const unsigned short* __restrict__ Wb,
    const float* __restrict__ cvec, const float* __restrict__ beta,
    float* __restrict__ out)
{
  __shared__ __align__(16) unsigned short Ai[4096];    // A-frag image, 8 KB (4 mtiles)
  __shared__ __align__(16) unsigned short Xc[5120];    // xc col-major s20, 10.25 KB
  __shared__ float rowacc[64];

  const int t = threadIdx.x;        // 0..511
  const int lane = t & 63;
  const int wv = t >> 6;            // 0..7
  const int q = lane >> 4;
  const int lr = lane & 15;
  const int rowBase = blockIdx.x * 64;

  // ---- staging: thread t covers row rl = t>>3, 8 cols seg*8.. ----
  {
    const int rl = t >> 3;          // 0..63
    const int s = t & 7;            // 0..7
    const int mtile = rl >> 4;
    const int mr = rl & 15;
    const float4_* src = (const float4_*)(x + (size_t)(rowBase + rl) * 64 + s * 8);
    const float4_ v0 = src[0], v1 = src[1];
    unsigned short h[8];
#pragma unroll
    for (int e = 0; e < 4; ++e) { h[e] = f2bf(v0[e]); h[4 + e] = f2bf(v1[e]); }
    // A-frag image: cols 8s..8s+7 -> record lane (q=s&3, lr=mr), half ks=s>>2
    short8 p;
#pragma unroll
    for (int e = 0; e < 8; ++e) p[e] = (short)h[e];
    *(short8*)&Ai[mtile * 1024 + ((s & 3) * 16 + mr) * 16 + (s >> 2) * 8] = p;
    // xc image: [col][mr], col stride 20 shorts
#pragma unroll
    for (int e = 0; e < 8; ++e)
      Xc[mtile * 1280 + (s * 8 + e) * 20 + mr] = h[e];
    if (t < 64) rowacc[t] = 0.0f;
  }
  __syncthreads();

  // ---- hoist A-frags to registers (one-time LDS read; 8 b128/wave) ----
  short8 a[4][2];
#pragma unroll
  for (int mt = 0; mt < 4; ++mt) {
    a[mt][0] = *(const short8*)&Ai[mt * 1024 + lane * 16];
    a[mt][1] = *(const short8*)&Ai[mt * 1024 + lane * 16 + 8];
  }

  float sacc[4][4] = {{0,0,0,0},{0,0,0,0},{0,0,0,0},{0,0,0,0}};

  // ---- comp loop: 8 comps per wave, b single-buffered ----
#pragma unroll 1
  for (int c = 0; c < 8; ++c) {
    const int k = wv * 8 + c;
    short8 b[2][4];
    {
      const unsigned short* wg = Wb + (size_t)k * 4096 + lane * 64;
#pragma unroll
      for (int ks = 0; ks < 2; ++ks)
#pragma unroll
        for (int t4 = 0; t4 < 4; ++t4)
          b[ks][t4] = *(const short8*)(wg + ks * 32 + t4 * 8);
    }
    float cc[4];
#pragma unroll
    for (int t4 = 0; t4 < 4; ++t4) cc[t4] = cvec[k * 64 + lr + 16 * t4];
    const float bk = beta[k];

#pragma unroll 2
    for (int mt = 0; mt < 4; ++mt) {
      uint2_ xq[4];
#pragma unroll
      for (int t4 = 0; t4 < 4; ++t4)
        xq[t4] = *(const uint2_*)&Xc[mt * 1280 + (lr + 16 * t4) * 20 + 4 * q];

      float4_ f[4];
#pragma unroll
      for (int t4 = 0; t4 < 4; ++t4) {
        const float cv = cc[t4];
        float4_ acc = {cv, cv, cv, cv};
        acc = __builtin_amdgcn_mfma_f32_16x16x32_bf16(a[mt][0], b[0][t4], acc, 0, 0, 0);
        acc = __builtin_amdgcn_mfma_f32_16x16x32_bf16(a[mt][1], b[1][t4], acc, 0, 0, 0);
        f[t4] = acc;
      }

      float xr[4][4];
#pragma unroll
      for (int t4 = 0; t4 < 4; ++t4) {
        xr[t4][0] = lo2f(xq[t4][0]);
        xr[t4][1] = hi2f(xq[t4][0]);
        xr[t4][2] = lo2f(xq[t4][1]);
        xr[t4][3] = hi2f(xq[t4][1]);
      }
#pragma unroll
      for (int r = 0; r < 4; ++r) {
        float sdot = xr[0][r] * f[0][r] + xr[1][r] * f[1][r]
                   + xr[2][r] * f[2][r] + xr[3][r] * f[3][r];
        sdot = dpp_add<0x121>(sdot);  // row_ror:1
        sdot = dpp_add<0x122>(sdot);  // row_ror:2
        sdot = dpp_add<0x124>(sdot);  // row_ror:4
        sdot = dpp_add<0x128>(sdot);  // row_ror:8
        sacc[mt][r] += exp2f(sdot + bk);
      }
    }
  }

  // ---- cross-wave combine (block-local) ----
  if (lr == 0) {
#pragma unroll
    for (int mt = 0; mt < 4; ++mt)
#pragma unroll
      for (int r = 0; r < 4; ++r)
        atomicAdd(&rowacc[mt * 16 + 4 * q + r], sacc[mt][r]);
  }
  __syncthreads();

  // ---- block finalizes its own 64 rows ----
  if (t < 64) {
    float v = __logf(rowacc[t]) - 90.0f;
#pragma unroll
    for (int d = 1; d < 64; d <<= 1) v += __shfl_xor(v, d, 64);
    if (t == 0) atomicAdd(out, -v * (1.0f / 32768.0f));
  }
}

extern "C" void kernel_launch(void* const* d_in, const int* in_sizes, int n_in,
                              void* d_out, int out_size, void* d_ws, size_t ws_size,
                              hipStream_t stream)
{
  const float* x           = (const float*)d_in[0];  // [32768,64]
  const float* means_raw   = (const float*)d_in[1];  // [64,64]
  const float* scale_raw   = (const float*)d_in[2];  // [64,64,64]
  const float* weights_raw = (const float*)d_in[3];  // [64]
  float* out = (float*)d_out;

  char* ws = (char*)d_ws;
  unsigned short* Wb = (unsigned short*)ws;             // 64*4096*2 = 524288 B
  float* cvec        = (float*)(ws + 524288);           // 16384 B
  float* beta        = (float*)(ws + 540672);           // 256 B

  gmm_setup<<<64, 256, 0, stream>>>(means_raw, scale_raw, weights_raw,
                                    Wb, cvec, beta, out);
  gmm_main<<<512, 512, 0, stream>>>(x, Wb, cvec, beta, out);
}

// Round 11
// 107.056 us; speedup vs baseline: 1.3306x; 1.3306x over previous
//
#include <hip/hip_runtime.h>

// B=32768, K=64, D=64, GAIN=1.0
#define LOG_2PI 1.8378770664093453f
#define LOG2E   1.4426950408889634f

typedef __attribute__((ext_vector_type(8))) short  short8;   // 8 x bf16
typedef __attribute__((ext_vector_type(4))) float  float4_;
typedef __attribute__((ext_vector_type(4))) unsigned uint4_;

__device__ __forceinline__ unsigned short f2bf(float f) {
  unsigned u = __builtin_bit_cast(unsigned, f);
  u += 0x7fffu + ((u >> 16) & 1u);   // RNE
  return (unsigned short)(u >> 16);
}
__device__ __forceinline__ float bf2f(unsigned short h) {
  return __builtin_bit_cast(float, ((unsigned)h) << 16);
}
__device__ __forceinline__ unsigned bits(float f) { return __builtin_bit_cast(unsigned, f); }
__device__ __forceinline__ float bitf(unsigned u) { return __builtin_bit_cast(float, u); }
// pack two f32 -> bf16x2 (lo,hi), truncating (in-loop; bias negligible, signs mixed)
__device__ __forceinline__ unsigned pk2(float lo, float hi) {
  return __builtin_amdgcn_perm(bits(hi), bits(lo), 0x07060302u);
}
// pack with round-half-up (one-time x conversion)
__device__ __forceinline__ unsigned pk2r(float lo, float hi) {
  return __builtin_amdgcn_perm(bits(hi) + 0x8000u, bits(lo) + 0x8000u, 0x07060302u);
}
template <int CTRL>
__device__ __forceinline__ float dpp_add(float v) {
  int t = __builtin_amdgcn_mov_dpp(__builtin_bit_cast(int, v), CTRL, 0xf, 0xf, true);
  return v + __builtin_bit_cast(float, t);
}
__device__ __forceinline__ void async16(const void* g, void* l) {
  __builtin_amdgcn_global_load_lds((const __attribute__((address_space(1))) unsigned int*)g,
                                   (__attribute__((address_space(3))) unsigned int*)l, 16, 0, 0);
}

// ---------------------------------------------------------------------------
// Feature space (76 chunks of 32, k-dim = 2432):
//  chunks 0..71: quadratic. bp = c>>1 in [0,36) enumerates (ib<=jb) 8x8 block
//    pairs; ks = c&1. Feature at (q-slice, slot j): i = 8*ib+4*ks+q, j2 = 8*jb+j.
//    A-value = x_i * x_j2 ; W = (ib==jb ? 1 : 2) * (-0.5*log2e) * M[i][j2].
//  chunk 72: linear, i = q+4j,      A = x_i, W = log2e*c_i
//  chunk 73: linear, i = q+32+4j,   A = x_i, W = log2e*c_i
//  chunk 74: const,  A = 1, W = beta' at (q0,j0) + residual at (q0,j1), else 0
//  chunk 75: zero pad.
// Wv layout (shorts): ((c*4 + nt)*64 + lane)*8 + slot  — exact B-frag order.
// ---------------------------------------------------------------------------

// Setup: one block per component k.
__global__ __launch_bounds__(256) void gmm_setup(
    const float* __restrict__ means_raw, const float* __restrict__ scale_raw,
    const float* __restrict__ weights_raw, unsigned short* __restrict__ Wv,
    float* __restrict__ out)
{
  const int k = blockIdx.x;
  const int t = threadIdx.x;
  const int lane = t & 63;
  const int wv = t >> 6;
  const int q = lane >> 4;
  const int jj = lane & 15;

  if (k == 0 && t == 0) out[0] = 0.0f;

  __shared__ float Plt[64][68];   // Plt[m][i] = L[i][m] for i>m, else 0
  __shared__ float Vt[64][68];    // Vt[c][m]  = Linv[m][c]
  __shared__ __align__(16) unsigned short Vb[64][72];  // bf16 Vt image
  __shared__ float Msh[64][65];   // fp32 M
  __shared__ float dg[64], rdg[64], mu_s[64], y_s[64], cs_[64];
  __shared__ float beta_s;

  {  // phase 1
    const int i = t >> 2;
    const int c0 = (t & 3) * 16;
    float4_ v4[4];
    const float4_* src = (const float4_*)(scale_raw + (size_t)k * 4096 + i * 64 + c0);
    v4[0] = src[0]; v4[1] = src[1]; v4[2] = src[2]; v4[3] = src[3];
#pragma unroll
    for (int e = 0; e < 16; ++e) {
      const int c = c0 + e;
      const float val = ((const float*)v4)[e] * (1.0f / 512.0f);
      Plt[c][i] = (c < i) ? val : 0.0f;
      if (c == i) { dg[i] = val; rdg[i] = __expf(-val); }
    }
  }
  if (t < 64) mu_s[t] = means_raw[k * 64 + t] * (1.0f / 64.0f);
  __syncthreads();

  // phase 2: forward substitution (col j = wv*16+jj, rows [16q,16q+16))
  {
    const int j = wv * 16 + jj;
    float s[16];
#pragma unroll
    for (int i = 0; i < 16; ++i) s[i] = 0.0f;
#pragma unroll
    for (int m = 0; m < 64; ++m) {
      const float rm = rdg[m];
      float vcand = (m == j) ? rm : -s[m & 15] * rm;
      const float v = __shfl(vcand, (m >> 4) * 16 + jj, 64);
      if (q == (m >> 4)) {
        Vt[j][m] = v;
        Vb[j][m] = f2bf(v);
      }
      const float4_* prow = (const float4_*)&Plt[m][16 * q];
      const float4_ p0 = prow[0], p1 = prow[1], p2 = prow[2], p3 = prow[3];
      s[0]  += p0[0] * v; s[1]  += p0[1] * v; s[2]  += p0[2] * v; s[3]  += p0[3] * v;
      s[4]  += p1[0] * v; s[5]  += p1[1] * v; s[6]  += p1[2] * v; s[7]  += p1[3] * v;
      s[8]  += p2[0] * v; s[9]  += p2[1] * v; s[10] += p2[2] * v; s[11] += p2[3] * v;
      s[12] += p3[0] * v; s[13] += p3[1] * v; s[14] += p3[2] * v; s[15] += p3[3] * v;
    }
  }
  __syncthreads();

  // phase 3a: M = V^T V via MFMA -> Msh (fp32)
  {
    const short8 a0 = *(const short8*)&Vb[16 * wv + jj][8 * q];
    const short8 a1 = *(const short8*)&Vb[16 * wv + jj][8 * q + 32];
#pragma unroll
    for (int t4 = 0; t4 < 4; ++t4) {
      const short8 b0 = *(const short8*)&Vb[jj + 16 * t4][8 * q];
      const short8 b1 = *(const short8*)&Vb[jj + 16 * t4][8 * q + 32];
      float4_ f = {0.f, 0.f, 0.f, 0.f};
      f = __builtin_amdgcn_mfma_f32_16x16x32_bf16(a0, b0, f, 0, 0, 0);
      f = __builtin_amdgcn_mfma_f32_16x16x32_bf16(a1, b1, f, 0, 0, 0);
#pragma unroll
      for (int r = 0; r < 4; ++r)
        Msh[16 * wv + 4 * q + r][jj + 16 * t4] = f[r];
    }
  }
  if (wv == 0) {  // y = V*mu
    float acc = 0.0f;
    for (int j2 = 0; j2 < 64; ++j2) acc += Vt[j2][lane] * mu_s[j2];
    y_s[lane] = acc;
  }
  __syncthreads();

  // tail: c' = log2e * V^T y -> cs_; beta' = log2e*(beta+90) -> beta_s
  if (t < 64) {
    const int i = t;
    float ci = 0.0f;
#pragma unroll
    for (int m4 = 0; m4 < 16; ++m4) {
      const float4_ a4 = *(const float4_*)&Vt[i][4 * m4];
      const float4_ b4 = *(const float4_*)&y_s[4 * m4];
      ci += a4[0] * b4[0] + a4[1] * b4[1] + a4[2] * b4[2] + a4[3] * b4[3];
    }
    cs_[i] = LOG2E * ci;
    float rq  = ci * mu_s[i];
    float dgv = dg[i];
    const float wr = weights_raw[i] * 0.125f;
    float mx = wr;
#pragma unroll
    for (int d = 1; d < 64; d <<= 1) mx = fmaxf(mx, __shfl_xor(mx, d, 64));
    float se = __expf(wr - mx);
#pragma unroll
    for (int d = 1; d < 64; d <<= 1) {
      se  += __shfl_xor(se, d, 64);
      rq  += __shfl_xor(rq, d, 64);
      dgv += __shfl_xor(dgv, d, 64);
    }
    if (i == 0) {
      const float wrk  = weights_raw[k] * 0.125f;
      const float logw = wrk - mx - __logf(se);
      const float bval = -0.5f * rq - 32.0f * LOG_2PI - dgv + logw;
      beta_s = LOG2E * (bval + 90.0f);
    }
  }
  __syncthreads();

  // Wv emission: this block writes its comp's column (nt = k>>4, lr = k&15)
  {
    const int nt = k >> 4, lrk = k & 15;
    const int j = t & 7, qq = (t >> 3) & 3, cs = t >> 5;  // 256 unique (cs,qq,j)
    for (int it = 0; it < 10; ++it) {
      const int c = cs + 8 * it;
      if (c >= 76) break;
      float val = 0.0f;
      if (c < 72) {
        const int bp = c >> 1, ks = c & 1;
        int rb = bp, ib = 0;
        while (rb >= 8 - ib) { rb -= (8 - ib); ++ib; }
        const int jb = ib + rb;
        const int i = 8 * ib + 4 * ks + qq, j2 = 8 * jb + j;
        val = (ib == jb ? 1.0f : 2.0f) * (-0.5f * LOG2E) * Msh[i][j2];
      } else if (c == 72) {
        val = cs_[qq + 4 * j];
      } else if (c == 73) {
        val = cs_[qq + 32 + 4 * j];
      } else if (c == 74) {
        if (qq == 0 && j == 0) val = beta_s;
        else if (qq == 0 && j == 1) val = beta_s - bf2f(f2bf(beta_s));  // residual
      }  // c == 75: zero pad
      Wv[(size_t)(c * 4 + nt) * 512 + (qq * 16 + lrk) * 8 + j] = f2bf(val);
    }
  }
}

// ---------------------------------------------------------------------------
// Main: 512 blocks x 256 threads (4 waves); wave owns 16 rows and ALL 64
// comps as ONE GEMM over the 2432-feature k-dim. A-frags built in-register
// from x (compile-time indices via block-pair layout); B staged from Wv via
// global_load_lds, 4-chunk groups double-buffered (19 barriers total).
// Epilogue: exp2/DPP/log ONCE per row (not per comp) — the R3..R9 per-comp
// VALU epilogue (~20 us device-wide) is gone.
// ---------------------------------------------------------------------------
__global__ __launch_bounds__(256) __attribute__((amdgpu_waves_per_eu(4, 4)))
void gmm_main(const float* __restrict__ x, const unsigned short* __restrict__ Wv,
              float* __restrict__ out)
{
  constexpr int IBt[36] = {0,0,0,0,0,0,0,0, 1,1,1,1,1,1,1, 2,2,2,2,2,2,
                           3,3,3,3,3, 4,4,4,4, 5,5,5, 6,6, 7};
  constexpr int JBt[36] = {0,1,2,3,4,5,6,7, 1,2,3,4,5,6,7, 2,3,4,5,6,7,
                           3,4,5,6,7, 4,5,6,7, 5,6,7, 6,7, 7};

  __shared__ __align__(16) unsigned short Wlds[2][8192];
  __shared__ float wsum[4];

  const int t = threadIdx.x;        // 0..255
  const int lane = t & 63;
  const int wv = t >> 6;            // 0..3
  const int q = lane >> 4;
  const int lr = lane & 15;
  const int row = blockIdx.x * 64 + wv * 16 + lr;

  // xBp[p] = bf16x2 {x[row][2p], x[row][2p+1]}  (round-half-up)
  unsigned xBp[32];
  {
    const float4_* xr4 = (const float4_*)(x + (size_t)row * 64);
#pragma unroll
    for (int m = 0; m < 16; ++m) {
      const float4_ v = xr4[m];
      xBp[2 * m]     = pk2r(v[0], v[1]);
      xBp[2 * m + 1] = pk2r(v[2], v[3]);
    }
  }
  // xAp[r] = bf16x2 {x[row][q+8r], x[row][q+8r+4]}   (xA[t] = x[q+4t])
  unsigned xAp[8];
  {
    const float* xr = x + (size_t)row * 64 + q;
#pragma unroll
    for (int r = 0; r < 8; ++r)
      xAp[r] = pk2r(xr[8 * r], xr[8 * r + 4]);
  }

  float4_ f[4] = {{0,0,0,0},{0,0,0,0},{0,0,0,0},{0,0,0,0}};

#define STAGE(gg)                                                              \
  {                                                                            \
    const unsigned short* src = Wv + 8192 * (gg) + wv * 2048 + lane * 8;       \
    unsigned short* dst = &Wlds[(gg) & 1][0] + wv * 2048 + lane * 8;           \
    async16(src, dst);                 async16(src + 512, dst + 512);          \
    async16(src + 1024, dst + 1024);   async16(src + 1536, dst + 1536);        \
  }

  STAGE(0)
  __syncthreads();

#pragma unroll
  for (int g = 0; g < 19; ++g) {
    if (g < 18) STAGE(g + 1)
    const unsigned short* wb = &Wlds[g & 1][0];
#pragma unroll
    for (int cl = 0; cl < 4; ++cl) {
      const int c = 4 * g + cl;
      if (c >= 75) continue;                 // chunk 75 = pad, skip
      short8 a;
      if (c < 72) {
        const int bp = c >> 1, ks = c & 1;
        const int ib = IBt[bp], jb = JBt[bp], tt = 2 * ib + ks;
        const unsigned ua = xAp[tt >> 1];
        const float xa = bitf((tt & 1) ? (ua & 0xffff0000u) : (ua << 16));
        uint4_ pk;
#pragma unroll
        for (int p = 0; p < 4; ++p) {
          const unsigned ub = xBp[4 * jb + p];
          const float b0 = bitf(ub << 16);
          const float b1 = bitf(ub & 0xffff0000u);
          pk[p] = pk2(xa * b0, xa * b1);
        }
        a = __builtin_bit_cast(short8, pk);
      } else if (c == 72) {
        uint4_ pk = {xAp[0], xAp[1], xAp[2], xAp[3]};
        a = __builtin_bit_cast(short8, pk);
      } else if (c == 73) {
        uint4_ pk = {xAp[4], xAp[5], xAp[6], xAp[7]};
        a = __builtin_bit_cast(short8, pk);
      } else {  // c == 74: constant-term chunk, A = 1.0
        uint4_ pk = {0x3f803f80u, 0x3f803f80u, 0x3f803f80u, 0x3f803f80u};
        a = __builtin_bit_cast(short8, pk);
      }
#pragma unroll
      for (int nt = 0; nt < 4; ++nt) {
        const short8 b = *(const short8*)(wb + cl * 2048 + nt * 512 + lane * 8);
        f[nt] = __builtin_amdgcn_mfma_f32_16x16x32_bf16(a, b, f[nt], 0, 0, 0);
      }
    }
    __syncthreads();
  }
#undef STAGE

  // epilogue (once per row): f[nt][r] = log2e*(val+90) for row q*4+r, comp nt*16+lr
  float v = 0.0f;
  {
    float s[4];
#pragma unroll
    for (int r = 0; r < 4; ++r) {
      float e = exp2f(f[0][r]) + exp2f(f[1][r]) + exp2f(f[2][r]) + exp2f(f[3][r]);
      e = dpp_add<0x121>(e);  // row_ror:1
      e = dpp_add<0x122>(e);  // row_ror:2
      e = dpp_add<0x124>(e);  // row_ror:4
      e = dpp_add<0x128>(e);  // row_ror:8
      s[r] = e;
    }
    if (lr == 0)
      v = (__logf(s[0]) + __logf(s[1]) + __logf(s[2]) + __logf(s[3])) - 360.0f;
    v += __shfl_xor(v, 16, 64);
    v += __shfl_xor(v, 32, 64);
  }
  if (lane == 0) wsum[wv] = v;
  __syncthreads();
  if (t == 0)
    atomicAdd(out, -(wsum[0] + wsum[1] + wsum[2] + wsum[3]) * (1.0f / 32768.0f));
}

extern "C" void kernel_launch(void* const* d_in, const int* in_sizes, int n_in,
                              void* d_out, int out_size, void* d_ws, size_t ws_size,
                              hipStream_t stream)
{
  const float* x           = (const float*)d_in[0];  // [32768,64]
  const float* means_raw   = (const float*)d_in[1];  // [64,64]
  const float* scale_raw   = (const float*)d_in[2];  // [64,64,64]
  const float* weights_raw = (const float*)d_in[3];  // [64]
  float* out = (float*)d_out;

  unsigned short* Wv = (unsigned short*)d_ws;   // 76*2048*2 = 311296 B

  gmm_setup<<<64, 256, 0, stream>>>(means_raw, scale_raw, weights_raw, Wv, out);
  gmm_main<<<512, 256, 0, stream>>>(x, Wv, out);
}

// Round 12
// 97.967 us; speedup vs baseline: 1.4540x; 1.0928x over previous
//
#include <hip/hip_runtime.h>

// B=32768, K=64, D=64, GAIN=1.0
#define LOG_2PI 1.8378770664093453f
#define LOG2E   1.4426950408889634f

typedef __attribute__((ext_vector_type(8))) short  short8;   // 8 x bf16
typedef __attribute__((ext_vector_type(4))) float  float4_;
typedef __attribute__((ext_vector_type(4))) unsigned uint4_;

__device__ __forceinline__ unsigned short f2bf(float f) {
  unsigned u = __builtin_bit_cast(unsigned, f);
  u += 0x7fffu + ((u >> 16) & 1u);   // RNE
  return (unsigned short)(u >> 16);
}
__device__ __forceinline__ float bf2f(unsigned short h) {
  return __builtin_bit_cast(float, ((unsigned)h) << 16);
}
__device__ __forceinline__ unsigned bits(float f) { return __builtin_bit_cast(unsigned, f); }
__device__ __forceinline__ float bitf(unsigned u) { return __builtin_bit_cast(float, u); }
// pack two f32 -> bf16x2 (lo,hi), truncating (in-loop; bias negligible, signs mixed)
__device__ __forceinline__ unsigned pk2(float lo, float hi) {
  return __builtin_amdgcn_perm(bits(hi), bits(lo), 0x07060302u);
}
// pack with round-half-up (one-time x conversion)
__device__ __forceinline__ unsigned pk2r(float lo, float hi) {
  return __builtin_amdgcn_perm(bits(hi) + 0x8000u, bits(lo) + 0x8000u, 0x07060302u);
}
template <int CTRL>
__device__ __forceinline__ float dpp_add(float v) {
  int t = __builtin_amdgcn_mov_dpp(__builtin_bit_cast(int, v), CTRL, 0xf, 0xf, true);
  return v + __builtin_bit_cast(float, t);
}
__device__ __forceinline__ void async16(const void* g, void* l) {
  __builtin_amdgcn_global_load_lds((const __attribute__((address_space(1))) unsigned int*)g,
                                   (__attribute__((address_space(3))) unsigned int*)l, 16, 0, 0);
}

// ---------------------------------------------------------------------------
// Feature space (78 chunks of 32 staged, 75 live; k-dim = 2432 live):
//  chunks 0..71: quadratic. bp = c>>1 in [0,36) enumerates (ib<=jb) 8x8 block
//    pairs; ks = c&1. Feature at (q-slice, slot j): i = 8*ib+4*ks+q, j2 = 8*jb+j.
//    A-value = x_i * x_j2 ; W = (ib==jb ? 1 : 2) * (-0.5*log2e) * M[i][j2].
//  chunk 72: linear, i = q+4j,      A = x_i, W = log2e*c_i
//  chunk 73: linear, i = q+32+4j,   A = x_i, W = log2e*c_i
//  chunk 74: const,  A = 1, W = beta' at (q0,j0) + residual at (q0,j1), else 0
//  chunks 75..77: zero pad (staged but never MFMA'd).
// Wv layout (shorts): ((c*4 + nt)*512) + (q*16 + lr)*8 + slot — B-frag order.
// ---------------------------------------------------------------------------

// Setup: one block per component k.
__global__ __launch_bounds__(256) void gmm_setup(
    const float* __restrict__ means_raw, const float* __restrict__ scale_raw,
    const float* __restrict__ weights_raw, unsigned short* __restrict__ Wv,
    float* __restrict__ out)
{
  constexpr int IBt[36] = {0,0,0,0,0,0,0,0, 1,1,1,1,1,1,1, 2,2,2,2,2,2,
                           3,3,3,3,3, 4,4,4,4, 5,5,5, 6,6, 7};
  constexpr int JBt[36] = {0,1,2,3,4,5,6,7, 1,2,3,4,5,6,7, 2,3,4,5,6,7,
                           3,4,5,6,7, 4,5,6,7, 5,6,7, 6,7, 7};

  const int k = blockIdx.x;
  const int t = threadIdx.x;
  const int lane = t & 63;
  const int wv = t >> 6;
  const int q = lane >> 4;
  const int jj = lane & 15;

  if (k == 0 && t == 0) out[0] = 0.0f;

  __shared__ float Plt[64][68];   // Plt[m][i] = L[i][m] for i>m, else 0
  __shared__ float Vt[64][68];    // Vt[c][m]  = Linv[m][c]
  __shared__ __align__(16) unsigned short Vb[64][72];  // bf16 Vt image
  __shared__ float Msh[64][65];   // fp32 M
  __shared__ float dg[64], rdg[64], mu_s[64], y_s[64], cs_[64];
  __shared__ float beta_s;

  {  // phase 1
    const int i = t >> 2;
    const int c0 = (t & 3) * 16;
    float4_ v4[4];
    const float4_* src = (const float4_*)(scale_raw + (size_t)k * 4096 + i * 64 + c0);
    v4[0] = src[0]; v4[1] = src[1]; v4[2] = src[2]; v4[3] = src[3];
#pragma unroll
    for (int e = 0; e < 16; ++e) {
      const int c = c0 + e;
      const float val = ((const float*)v4)[e] * (1.0f / 512.0f);
      Plt[c][i] = (c < i) ? val : 0.0f;
      if (c == i) { dg[i] = val; rdg[i] = __expf(-val); }
    }
  }
  if (t < 64) mu_s[t] = means_raw[k * 64 + t] * (1.0f / 64.0f);
  __syncthreads();

  // phase 2: forward substitution (col j = wv*16+jj, rows [16q,16q+16))
  {
    const int j = wv * 16 + jj;
    float s[16];
#pragma unroll
    for (int i = 0; i < 16; ++i) s[i] = 0.0f;
#pragma unroll
    for (int m = 0; m < 64; ++m) {
      const float rm = rdg[m];
      float vcand = (m == j) ? rm : -s[m & 15] * rm;
      const float v = __shfl(vcand, (m >> 4) * 16 + jj, 64);
      if (q == (m >> 4)) {
        Vt[j][m] = v;
        Vb[j][m] = f2bf(v);
      }
      const float4_* prow = (const float4_*)&Plt[m][16 * q];
      const float4_ p0 = prow[0], p1 = prow[1], p2 = prow[2], p3 = prow[3];
      s[0]  += p0[0] * v; s[1]  += p0[1] * v; s[2]  += p0[2] * v; s[3]  += p0[3] * v;
      s[4]  += p1[0] * v; s[5]  += p1[1] * v; s[6]  += p1[2] * v; s[7]  += p1[3] * v;
      s[8]  += p2[0] * v; s[9]  += p2[1] * v; s[10] += p2[2] * v; s[11] += p2[3] * v;
      s[12] += p3[0] * v; s[13] += p3[1] * v; s[14] += p3[2] * v; s[15] += p3[3] * v;
    }
  }
  __syncthreads();

  // phase 3a: M = V^T V via MFMA -> Msh (fp32)
  {
    const short8 a0 = *(const short8*)&Vb[16 * wv + jj][8 * q];
    const short8 a1 = *(const short8*)&Vb[16 * wv + jj][8 * q + 32];
#pragma unroll
    for (int t4 = 0; t4 < 4; ++t4) {
      const short8 b0 = *(const short8*)&Vb[jj + 16 * t4][8 * q];
      const short8 b1 = *(const short8*)&Vb[jj + 16 * t4][8 * q + 32];
      float4_ f = {0.f, 0.f, 0.f, 0.f};
      f = __builtin_amdgcn_mfma_f32_16x16x32_bf16(a0, b0, f, 0, 0, 0);
      f = __builtin_amdgcn_mfma_f32_16x16x32_bf16(a1, b1, f, 0, 0, 0);
#pragma unroll
      for (int r = 0; r < 4; ++r)
        Msh[16 * wv + 4 * q + r][jj + 16 * t4] = f[r];
    }
  }
  if (wv == 0) {  // y = V*mu
    float acc = 0.0f;
    for (int j2 = 0; j2 < 64; ++j2) acc += Vt[j2][lane] * mu_s[j2];
    y_s[lane] = acc;
  }
  __syncthreads();

  // tail: c' = log2e * V^T y -> cs_; beta' = log2e*(beta+90) -> beta_s
  if (t < 64) {
    const int i = t;
    float ci = 0.0f;
#pragma unroll
    for (int m4 = 0; m4 < 16; ++m4) {
      const float4_ a4 = *(const float4_*)&Vt[i][4 * m4];
      const float4_ b4 = *(const float4_*)&y_s[4 * m4];
      ci += a4[0] * b4[0] + a4[1] * b4[1] + a4[2] * b4[2] + a4[3] * b4[3];
    }
    cs_[i] = LOG2E * ci;
    float rq  = ci * mu_s[i];
    float dgv = dg[i];
    const float wr = weights_raw[i] * 0.125f;
    float mx = wr;
#pragma unroll
    for (int d = 1; d < 64; d <<= 1) mx = fmaxf(mx, __shfl_xor(mx, d, 64));
    float se = __expf(wr - mx);
#pragma unroll
    for (int d = 1; d < 64; d <<= 1) {
      se  += __shfl_xor(se, d, 64);
      rq  += __shfl_xor(rq, d, 64);
      dgv += __shfl_xor(dgv, d, 64);
    }
    if (i == 0) {
      const float wrk  = weights_raw[k] * 0.125f;
      const float logw = wrk - mx - __logf(se);
      const float bval = -0.5f * rq - 32.0f * LOG_2PI - dgv + logw;
      beta_s = LOG2E * (bval + 90.0f);
    }
  }
  __syncthreads();

  // Wv emission (coalesced): item m = (c, qq); thread t does m = t, t + 256.
  // One b128 store of 8 contiguous slots per item (vs R11's scattered shorts).
  {
    const int nt = k >> 4, lrk = k & 15;
#pragma unroll
    for (int half = 0; half < 2; ++half) {
      const int m = t + half * 256;
      if (m < 312) {                      // 78 chunks x 4 q-slices
        const int c = m >> 2, qq = m & 3;
        unsigned short h8[8];
#pragma unroll
        for (int e = 0; e < 8; ++e) h8[e] = 0;
        if (c < 72) {
          const int bp = c >> 1, ks = c & 1;
          const int ib = IBt[bp], jb = JBt[bp];
          const int i = 8 * ib + 4 * ks + qq;
          const float sc = (ib == jb ? 1.0f : 2.0f) * (-0.5f * LOG2E);
#pragma unroll
          for (int e = 0; e < 8; ++e) h8[e] = f2bf(sc * Msh[i][8 * jb + e]);
        } else if (c == 72) {
#pragma unroll
          for (int e = 0; e < 8; ++e) h8[e] = f2bf(cs_[qq + 4 * e]);
        } else if (c == 73) {
#pragma unroll
          for (int e = 0; e < 8; ++e) h8[e] = f2bf(cs_[qq + 32 + 4 * e]);
        } else if (c == 74) {
          if (qq == 0) {
            h8[0] = f2bf(beta_s);
            h8[1] = f2bf(beta_s - bf2f(f2bf(beta_s)));   // residual
          }
        }  // c in 75..77: zero pad
        uint4_ pkd;
#pragma unroll
        for (int p = 0; p < 4; ++p)
          pkd[p] = (unsigned)h8[2 * p] | ((unsigned)h8[2 * p + 1] << 16);
        *(uint4_*)&Wv[(size_t)(c * 4 + nt) * 512 + (qq * 16 + lrk) * 8] = pkd;
      }
    }
  }
}

// ---------------------------------------------------------------------------
// Main: 512 blocks x 256 threads (4 waves); wave owns 16 rows and ALL 64
// comps as ONE GEMM over the 2432-feature k-dim. A-frags built in-register
// from x; B staged from Wv via global_load_lds in 6-chunk double-buffered
// groups (13 barriers; LDS 48 KB, 2 blocks/CU = 96 KB). waves_per_eu(2,2):
// the 512-block grid caps at 2 waves/EU anyway, so pinning (2,2) gives the
// allocator the full 256-reg budget — no silent spill (R5/R6/R10 lesson).
// ---------------------------------------------------------------------------
__global__ __launch_bounds__(256) __attribute__((amdgpu_waves_per_eu(2, 2)))
void gmm_main(const float* __restrict__ x, const unsigned short* __restrict__ Wv,
              float* __restrict__ out)
{
  constexpr int IBt[36] = {0,0,0,0,0,0,0,0, 1,1,1,1,1,1,1, 2,2,2,2,2,2,
                           3,3,3,3,3, 4,4,4,4, 5,5,5, 6,6, 7};
  constexpr int JBt[36] = {0,1,2,3,4,5,6,7, 1,2,3,4,5,6,7, 2,3,4,5,6,7,
                           3,4,5,6,7, 4,5,6,7, 5,6,7, 6,7, 7};

  __shared__ __align__(16) unsigned short Wlds[2][12288];   // 2 x 24 KB
  __shared__ float wsum[4];

  const int t = threadIdx.x;        // 0..255
  const int lane = t & 63;
  const int wv = t >> 6;            // 0..3
  const int q = lane >> 4;
  const int lr = lane & 15;
  const int row = blockIdx.x * 64 + wv * 16 + lr;

  // xBp[p] = bf16x2 {x[row][2p], x[row][2p+1]}  (round-half-up)
  unsigned xBp[32];
  {
    const float4_* xr4 = (const float4_*)(x + (size_t)row * 64);
#pragma unroll
    for (int m = 0; m < 16; ++m) {
      const float4_ v = xr4[m];
      xBp[2 * m]     = pk2r(v[0], v[1]);
      xBp[2 * m + 1] = pk2r(v[2], v[3]);
    }
  }
  // xAp[r] = bf16x2 {x[row][q+8r], x[row][q+8r+4]}   (xA[t] = x[q+4t])
  unsigned xAp[8];
  {
    const float* xr = x + (size_t)row * 64 + q;
#pragma unroll
    for (int r = 0; r < 8; ++r)
      xAp[r] = pk2r(xr[8 * r], xr[8 * r + 4]);
  }

  float4_ f[4] = {{0,0,0,0},{0,0,0,0},{0,0,0,0},{0,0,0,0}};

#define STAGE(gg)                                                              \
  {                                                                            \
    const unsigned short* src = Wv + 12288 * (gg) + t * 8;                     \
    unsigned short* dst = &Wlds[(gg) & 1][0] + t * 8;                          \
    async16(src, dst);                 async16(src + 2048,  dst + 2048);       \
    async16(src + 4096,  dst + 4096);  async16(src + 6144,  dst + 6144);       \
    async16(src + 8192,  dst + 8192);  async16(src + 10240, dst + 10240);      \
  }

  STAGE(0)
  __syncthreads();

#pragma unroll
  for (int g = 0; g < 13; ++g) {
    if (g < 12) STAGE(g + 1)
    const unsigned short* wb = &Wlds[g & 1][0];
#pragma unroll
    for (int cl = 0; cl < 6; ++cl) {
      const int c = 6 * g + cl;
      if (c >= 75) continue;                 // chunks 75..77 = pad
      short8 a;
      if (c < 72) {
        const int bp = c >> 1, ks = c & 1;
        const int ib = IBt[bp], jb = JBt[bp], tt = 2 * ib + ks;
        const unsigned ua = xAp[tt >> 1];
        const float xa = bitf((tt & 1) ? (ua & 0xffff0000u) : (ua << 16));
        uint4_ pk;
#pragma unroll
        for (int p = 0; p < 4; ++p) {
          const unsigned ub = xBp[4 * jb + p];
          const float b0 = bitf(ub << 16);
          const float b1 = bitf(ub & 0xffff0000u);
          pk[p] = pk2(xa * b0, xa * b1);
        }
        a = __builtin_bit_cast(short8, pk);
      } else if (c == 72) {
        uint4_ pk = {xAp[0], xAp[1], xAp[2], xAp[3]};
        a = __builtin_bit_cast(short8, pk);
      } else if (c == 73) {
        uint4_ pk = {xAp[4], xAp[5], xAp[6], xAp[7]};
        a = __builtin_bit_cast(short8, pk);
      } else {  // c == 74: constant-term chunk, A = 1.0
        uint4_ pk = {0x3f803f80u, 0x3f803f80u, 0x3f803f80u, 0x3f803f80u};
        a = __builtin_bit_cast(short8, pk);
      }
#pragma unroll
      for (int nt = 0; nt < 4; ++nt) {
        const short8 b = *(const short8*)(wb + cl * 2048 + nt * 512 + lane * 8);
        f[nt] = __builtin_amdgcn_mfma_f32_16x16x32_bf16(a, b, f[nt], 0, 0, 0);
      }
    }
    __syncthreads();
  }
#undef STAGE

  // epilogue (once per row): f[nt][r] = log2e*(val+90) for row q*4+r, comp nt*16+lr
  float v = 0.0f;
  {
    float s[4];
#pragma unroll
    for (int r = 0; r < 4; ++r) {
      float e = exp2f(f[0][r]) + exp2f(f[1][r]) + exp2f(f[2][r]) + exp2f(f[3][r]);
      e = dpp_add<0x121>(e);  // row_ror:1
      e = dpp_add<0x122>(e);  // row_ror:2
      e = dpp_add<0x124>(e);  // row_ror:4
      e = dpp_add<0x128>(e);  // row_ror:8
      s[r] = e;
    }
    if (lr == 0)
      v = (__logf(s[0]) + __logf(s[1]) + __logf(s[2]) + __logf(s[3])) - 360.0f;
    v += __shfl_xor(v, 16, 64);
    v += __shfl_xor(v, 32, 64);
  }
  if (lane == 0) wsum[wv] = v;
  __syncthreads();
  if (t == 0)
    atomicAdd(out, -(wsum[0] + wsum[1] + wsum[2] + wsum[3]) * (1.0f / 32768.0f));
}

extern "C" void kernel_launch(void* const* d_in, const int* in_sizes, int n_in,
                              void* d_out, int out_size, void* d_ws, size_t ws_size,
                              hipStream_t stream)
{
  const float* x           = (const float*)d_in[0];  // [32768,64]
  const float* means_raw   = (const float*)d_in[1];  // [64,64]
  const float* scale_raw   = (const float*)d_in[2];  // [64,64,64]
  const float* weights_raw = (const float*)d_in[3];  // [64]
  float* out = (float*)d_out;

  unsigned short* Wv = (unsigned short*)d_ws;   // 78*2048*2 = 319488 B

  gmm_setup<<<64, 256, 0, stream>>>(means_raw, scale_raw, weights_raw, Wv, out);
  gmm_main<<<512, 256, 0, stream>>>(x, Wv, out);
}